// Round 5
// baseline (257.514 us; speedup 1.0000x reference)
//
#include <hip/hip_runtime.h>
#include <math.h>

#define B_ 2
#define S_ 128
#define H_ 4
#define DK_ 128
#define NB_ 4
#define D_ 512
#define M_ 256   // B_*S_

typedef __attribute__((ext_vector_type(8))) short short8;
typedef __attribute__((ext_vector_type(4))) float float4v;

__device__ __forceinline__ float elu1(float x) {
    return (x > 0.f) ? (x + 1.f) : __expf(x);
}

__device__ __forceinline__ unsigned short f2bf(float f) {
    unsigned u = __float_as_uint(f);
    unsigned r = (u + 0x7FFFu + ((u >> 16) & 1u)) >> 16;
    return (unsigned short)r;
}

// ---------------------------------------------------------------------------
// ws layout (float offsets)
//  qkv    : 786432   @ 0        (q1,k1,v1,q2,k2,v2 each [256,512]; o>=3 elu'd)
//  pq     : 131072   @ 786432
//  pk     : 131072   @ 917504
//  bbq    : 16384    @ 1048576
//  bbk    : 16384    @ 1064960
//  A_m    : 131072   @ 1081344  (bf16 [256][1024])
//  A_c    : 131072   @ 1212416
//  Wt     : 1572864  @ 1343488  (bf16 [6][512][1024], n-major)
//  wm_bf  : 131072   @ 2916352  (bf16 [512][512], [n][k])
//  wc_bf  : 131072   @ 3047424
//  mctxb  : 65536    @ 3178496  (bf16 [256][512])
//  cctxb  : 65536    @ 3244032
//  total  : 3309568 floats = 13.2 MB
// ---------------------------------------------------------------------------

union __attribute__((aligned(16))) PrepSMem {
    unsigned short tile[32][33];
    struct { float ps[2][8][128]; float wsh[2][128][33]; } c;
};

// ① prep: bf16 conversions + projection-weight transpose + small lins.
//    All three parts are independent (read only inputs, write disjoint ws).
__global__ __launch_bounds__(256) void k_prep(
    const float* __restrict__ x_m, const float* __restrict__ b_m,
    const float* __restrict__ x_c, const float* __restrict__ b_c,
    const float* __restrict__ mean_w, const float* __restrict__ cov_w,
    const float* __restrict__ W_xm, const float* __restrict__ W_xc,
    const float* __restrict__ W_bm, const float* __restrict__ W_bc,
    const float* __restrict__ p_m, const float* __restrict__ bb_m,
    const float* __restrict__ Wq2, const float* __restrict__ bq2,
    const float* __restrict__ Wk2, const float* __restrict__ bk2,
    const float* __restrict__ Wq1, const float* __restrict__ bq1,
    const float* __restrict__ Wk1, const float* __restrict__ bk1,
    unsigned short* __restrict__ A_m, unsigned short* __restrict__ A_c,
    unsigned short* __restrict__ wm_bf, unsigned short* __restrict__ wc_bf,
    unsigned short* __restrict__ Wt,
    float* __restrict__ pq, float* __restrict__ pk,
    float* __restrict__ bbq, float* __restrict__ bbk)
{
    __shared__ PrepSMem sm;
    const int t = threadIdx.x;
    const int blk = blockIdx.x;
    const int u2 = t >> 7, tl = t & 127;

    // A: bf16 conversions (A_m, A_c, wm_bf, wc_bf)
    {
        const int gid = blk * 256 + t;
#pragma unroll
        for (int u = 0; u < 16; ++u) {
            int e = u * 65536 + gid;
            int job = e >> 18, off = e & 262143;
            float v; unsigned short* dst;
            if (job == 0) {
                int m = off >> 10, k = off & 1023;
                v = (k < 512) ? x_m[m * 512 + k] : b_m[m * 512 + k - 512];
                dst = A_m;
            } else if (job == 1) {
                int m = off >> 10, k = off & 1023;
                v = (k < 512) ? x_c[m * 512 + k] : b_c[m * 512 + k - 512];
                dst = A_c;
            } else if (job == 2) { v = mean_w[off]; dst = wm_bf; }
            else                 { v = cov_w[off];  dst = wc_bf; }
            dst[off] = f2bf(v);
        }
    }
    // B: projection-weight transpose+convert -> Wt[o][n][k]
    {
        const int tx = t & 31, ty = t >> 5;
        for (int it = 0; it < 12; ++it) {
            int tid = blk * 12 + it;
            int nt = tid & 15, kt = (tid >> 4) & 15, z = tid >> 8;
            int o = z >> 1, part = z & 1;
            const float* src;
            if (part == 0) src = (o < 3) ? (W_xm + o * 262144) : (W_xc + (o - 3) * 262144);
            else           src = (o < 3) ? (W_bm + o * 262144) : (W_bc + (o - 3) * 262144);
            __syncthreads();
#pragma unroll
            for (int u = 0; u < 4; ++u)
                sm.tile[ty + u * 8][tx] = f2bf(src[(kt * 32 + ty + u * 8) * 512 + nt * 32 + tx]);
            __syncthreads();
            unsigned short* dst = Wt + o * 524288 + part * 512;
#pragma unroll
            for (int u = 0; u < 4; ++u)
                dst[(nt * 32 + ty + u * 8) * 1024 + kt * 32 + tx] = sm.tile[tx][ty + u * 8];
        }
    }
    __syncthreads();
    // C: small 128x128 lins (pq, pk, bbq, bbk); 2 half-block units, blk<144
    if (blk < 144) {
        const int cunit = blk * 2 + u2;
        const float *src, *Wm, *bias; float* dst; int row0;
        if (cunit < 128)      { src = p_m;  Wm = Wq2; bias = bq2; dst = pq;  row0 = cunit * 8; }
        else if (cunit < 256) { src = p_m;  Wm = Wk2; bias = bk2; dst = pk;  row0 = (cunit - 128) * 8; }
        else if (cunit < 272) { src = bb_m; Wm = Wq1; bias = bq1; dst = bbq; row0 = (cunit - 256) * 8; }
        else                  { src = bb_m; Wm = Wk1; bias = bk1; dst = bbk; row0 = (cunit - 272) * 8; }

        float (*ps)[128] = sm.c.ps[u2];
        float (*wsh)[33] = sm.c.wsh[u2];
#pragma unroll
        for (int r = 0; r < 8; ++r) ps[r][tl] = src[(row0 + r) * 128 + tl];

        float acc[8];
#pragma unroll
        for (int r = 0; r < 8; ++r) acc[r] = 0.f;

        const int kc = tl & 31, kr0 = tl >> 5;
        for (int c0 = 0; c0 < 128; c0 += 32) {
            __syncthreads();
#pragma unroll 8
            for (int u = 0; u < 32; ++u)
                wsh[kr0 + u * 4][kc] = Wm[(kr0 + u * 4) * 128 + c0 + kc];
            __syncthreads();
#pragma unroll 8
            for (int k2 = 0; k2 < 32; ++k2) {
                float wvv = wsh[tl][k2];
#pragma unroll
                for (int r = 0; r < 8; ++r)
                    acc[r] = fmaf(ps[r][c0 + k2], wvv, acc[r]);
            }
        }
        float bv = bias[tl];
#pragma unroll
        for (int r = 0; r < 8; ++r) dst[(row0 + r) * 128 + tl] = acc[r] + bv;
    }
}

// ② MFMA projection GEMM (proven R3 body): one wave per 16x16 tile, K=1024.
__global__ __launch_bounds__(256) void k_mm(
    const unsigned short* __restrict__ A_m, const unsigned short* __restrict__ A_c,
    const unsigned short* __restrict__ Wt, float* __restrict__ qkv)
{
    const int t = threadIdx.x;
    const int wid = blockIdx.x * 4 + (t >> 6);
    const int lane = t & 63;
    const int o = wid >> 9;
    const int rem = wid & 511;
    const int nt = rem & 31, mt = rem >> 5;
    const int m0 = mt * 16, n0 = nt * 16;
    const int l15 = lane & 15, quad = lane >> 4;

    const unsigned short* A = (o < 3) ? A_m : A_c;
    const unsigned short* ap = A + (m0 + l15) * 1024 + quad * 8;
    const unsigned short* bp = Wt + o * 524288 + (n0 + l15) * 1024 + quad * 8;

    float4v acc0 = {0.f, 0.f, 0.f, 0.f};
    float4v acc1 = {0.f, 0.f, 0.f, 0.f};
#pragma unroll
    for (int k0 = 0; k0 < 1024; k0 += 64) {
        short8 a0 = *(const short8*)(ap + k0);
        short8 b0 = *(const short8*)(bp + k0);
        short8 a1 = *(const short8*)(ap + k0 + 32);
        short8 b1 = *(const short8*)(bp + k0 + 32);
        acc0 = __builtin_amdgcn_mfma_f32_16x16x32_bf16(a0, b0, acc0, 0, 0, 0);
        acc1 = __builtin_amdgcn_mfma_f32_16x16x32_bf16(a1, b1, acc1, 0, 0, 0);
    }

    float* dst = qkv + o * 131072;
#pragma unroll
    for (int r = 0; r < 4; ++r) {
        float v = acc0[r] + acc1[r];
        if (o >= 3) v = elu1(v);
        dst[(m0 + quad * 4 + r) * 512 + n0 + l15] = v;
    }
}

// ③ attn with inlined tri-SAGP fuse. Block = (i, h, b), 128 threads.
//    fQ(i, sv=0..3) -> LDS; fK(si, j=t, :) recomputed in the w2 loop.
__global__ __launch_bounds__(128) void k_attn2(
    const float* __restrict__ qkv, const float* __restrict__ pq,
    const float* __restrict__ pk, const float* __restrict__ bbq,
    const float* __restrict__ bbk, const float* __restrict__ bb_c,
    const float* __restrict__ p_c, const int* __restrict__ b_seq,
    float* __restrict__ probs_out, unsigned short* __restrict__ mctxb,
    unsigned short* __restrict__ cctxb)
{
    const int t = threadIdx.x;
    const int i = blockIdx.x, h = blockIdx.y, b = blockIdx.z;
    const float eps = 1e-24f;

    __shared__ __attribute__((aligned(16))) float qm[4 * 132];
    __shared__ __attribute__((aligned(16))) float qs[4 * 132];
    __shared__ float red[4];
    __shared__ float pr[128], pr2[128];

    const int si = b_seq[b * S_ + i];
    const int sj = b_seq[b * S_ + t];

    // ---- fQ(i, sv) into LDS (thread t = dim k) ----
    {
        const int d = h * 128 + t;
        const int base = (b * S_ + i) * D_ + d;
        float m1 = qkv[base];
        float c1 = qkv[3 * M_ * D_ + base];   // q2 (elu'd in k_mm)
        float m3 = pq[base];
        float c3 = p_c[base];
        float p1 = 1.f / fmaxf(c1, eps);
        float p3 = 1.f / fmaxf(c3, eps);
        float mp13 = m1 * p1 + m3 * p3;
#pragma unroll
        for (int sv = 0; sv < 4; ++sv) {
            int idx = (b * 16 + sv * 4 + si) * 512 + d;   // n1=sv, n2=seq[i]
            float m2 = bbq[idx];
            float c2 = bb_c[idx];
            float p2 = 1.f / fmaxf(c2, eps);
            float cc = 1.f / (p1 + p2 + p3);
            qm[sv * 132 + t] = cc * (mp13 + m2 * p2);
            qs[sv * 132 + t] = sqrtf(fmaxf(cc, eps));
        }
    }
    __syncthreads();

    // ---- fK(si, j=t, k) recomputed inline, fused with W2 distance ----
    const int jbase = (b * S_ + t) * D_ + h * 128;
    const float4* k1p = (const float4*)(qkv + M_ * D_ + jbase);
    const float4* k2p = (const float4*)(qkv + 4 * M_ * D_ + jbase);
    const float4* pkp = (const float4*)(pk + jbase);
    const float4* pcp = (const float4*)(p_c + jbase);
    const int tb = (b * 16 + sj * 4 + si) * 512 + h * 128;   // n1=seq[j], n2=si
    const float4* bkp = (const float4*)(bbk + tb);
    const float4* bcp = (const float4*)(bb_c + tb);

    float w2 = 0.f;
#pragma unroll 4
    for (int k4 = 0; k4 < 32; ++k4) {
        float4 m1v = k1p[k4];
        float4 c1v = k2p[k4];
        float4 m3v = pkp[k4];
        float4 c3v = pcp[k4];
        float4 m2v = bkp[k4];
        float4 c2v = bcp[k4];
        float4 qmv = *(const float4*)&qm[sj * 132 + k4 * 4];
        float4 qsv = *(const float4*)&qs[sj * 132 + k4 * 4];
        float dd[4], ee[4];
#pragma unroll
        for (int c = 0; c < 4; ++c) {
            float m1 = ((const float*)&m1v)[c], c1 = ((const float*)&c1v)[c];
            float m3 = ((const float*)&m3v)[c], c3 = ((const float*)&c3v)[c];
            float m2 = ((const float*)&m2v)[c], c2 = ((const float*)&c2v)[c];
            float p1 = 1.f / fmaxf(c1, eps);
            float p2 = 1.f / fmaxf(c2, eps);
            float p3 = 1.f / fmaxf(c3, eps);
            float cc = 1.f / (p1 + p2 + p3);
            float fm = cc * (m1 * p1 + m2 * p2 + m3 * p3);
            float fs = sqrtf(fmaxf(cc, eps));
            dd[c] = ((const float*)&qmv)[c] - fm;
            ee[c] = ((const float*)&qsv)[c] - fs;
        }
        w2 += dd[0] * dd[0] + dd[1] * dd[1] + dd[2] * dd[2] + dd[3] * dd[3]
            + ee[0] * ee[0] + ee[1] * ee[1] + ee[2] * ee[2] + ee[3] * ee[3];
    }
    float score = -w2 * 0.08838834764831845f;   // 1/sqrt(128)

    // ---- softmax over 128 threads (2 waves) ----
    float mx = score;
#pragma unroll
    for (int off = 32; off >= 1; off >>= 1) mx = fmaxf(mx, __shfl_xor(mx, off));
    if ((t & 63) == 0) red[t >> 6] = mx;
    __syncthreads();
    mx = fmaxf(red[0], red[1]);
    float e = __expf(score - mx);
    float sm = e;
#pragma unroll
    for (int off = 32; off >= 1; off >>= 1) sm += __shfl_xor(sm, off);
    if ((t & 63) == 0) red[2 + (t >> 6)] = sm;
    __syncthreads();
    float p = e / (red[2] + red[3]);

    probs_out[((b * H_ + h) * S_ + i) * S_ + t] = p;
    pr[t] = p;
    pr2[t] = p * p;
    __syncthreads();

    // ---- ctx (thread t = dim k) ----
    const float* v1 = qkv + 2 * M_ * D_ + (b * S_) * D_ + h * 128 + t;
    const float* v2 = qkv + 5 * M_ * D_ + (b * S_) * D_ + h * 128 + t;
    float am = 0.f, ac = 0.f;
#pragma unroll 8
    for (int j = 0; j < 128; ++j) {
        am = fmaf(pr[j], v1[j * D_], am);
        ac = fmaf(pr2[j], v2[j * D_], ac);
    }
    mctxb[(b * S_ + i) * D_ + h * 128 + t] = f2bf(am);
    cctxb[(b * S_ + i) * D_ + h * 128 + t] = f2bf(ac);
}

// ④ fused epilogue: MFMA GEMM (y into LDS) + bias + residual + LN -> out.
//    Block = (mat, mtile of 16 rows); 32 blocks x 256 threads.
__global__ __launch_bounds__(256) void k_fin(
    const unsigned short* __restrict__ mctxb, const unsigned short* __restrict__ cctxb,
    const unsigned short* __restrict__ wm_bf, const unsigned short* __restrict__ wc_bf,
    const float* __restrict__ mean_b, const float* __restrict__ cov_b,
    const float* __restrict__ x_m, const float* __restrict__ x_c,
    const float* __restrict__ ln_w, const float* __restrict__ ln_b,
    float* __restrict__ out)
{
    const int mat = blockIdx.x >> 4, mt = blockIdx.x & 15;
    const int m0 = mt * 16;
    const unsigned short* A = mat ? cctxb : mctxb;
    const unsigned short* Bw = mat ? wc_bf : wm_bf;

    __shared__ float y[16][516];   // +4 pad: r*516 % 32 = 4r -> spread banks

    const int t = threadIdx.x;
    const int wv = t >> 6, lane = t & 63;
    const int l15 = lane & 15, quad = lane >> 4;

    const unsigned short* ap = A + (m0 + l15) * 512 + quad * 8;
#pragma unroll
    for (int u = 0; u < 8; ++u) {
        int n0 = (wv * 8 + u) * 16;
        const unsigned short* bp = Bw + (n0 + l15) * 512 + quad * 8;
        float4v acc0 = {0.f, 0.f, 0.f, 0.f};
        float4v acc1 = {0.f, 0.f, 0.f, 0.f};
#pragma unroll
        for (int k0 = 0; k0 < 512; k0 += 64) {
            short8 a0 = *(const short8*)(ap + k0);
            short8 b0 = *(const short8*)(bp + k0);
            short8 a1 = *(const short8*)(ap + k0 + 32);
            short8 b1 = *(const short8*)(bp + k0 + 32);
            acc0 = __builtin_amdgcn_mfma_f32_16x16x32_bf16(a0, b0, acc0, 0, 0, 0);
            acc1 = __builtin_amdgcn_mfma_f32_16x16x32_bf16(a1, b1, acc1, 0, 0, 0);
        }
#pragma unroll
        for (int r = 0; r < 4; ++r)
            y[quad * 4 + r][n0 + l15] = acc0[r] + acc1[r];
    }
    __syncthreads();

    // LN: thread (r = t>>4, c = t&15): 32 cols each, 16-lane shuffle reduce.
    const int r = t >> 4, c = t & 15;
    const int row = m0 + r;
    const float* bias = mat ? cov_b : mean_b;
    const float* res = mat ? x_c : x_m;

    float vals[32];
    float s = 0.f, ss = 0.f;
#pragma unroll
    for (int u = 0; u < 32; ++u) {
        int col = c + 16 * u;
        float v = y[r][col] + bias[col] + res[row * 512 + col];
        vals[u] = v;
        s += v; ss += v * v;
    }
#pragma unroll
    for (int off = 8; off >= 1; off >>= 1) {
        s += __shfl_xor(s, off);
        ss += __shfl_xor(ss, off);
    }
    float mu = s * (1.f / 512.f);
    float var = ss * (1.f / 512.f) - mu * mu;
    float rstd = 1.f / sqrtf(var + 1e-12f);
#pragma unroll
    for (int u = 0; u < 32; ++u) {
        int col = c + 16 * u;
        out[mat * 131072 + row * 512 + col] = (vals[u] - mu) * rstd * ln_w[col] + ln_b[col];
    }
}

extern "C" void kernel_launch(void* const* d_in, const int* in_sizes, int n_in,
                              void* d_out, int out_size, void* d_ws, size_t ws_size,
                              hipStream_t stream) {
    (void)in_sizes; (void)n_in; (void)out_size; (void)ws_size;
    const float* x_m   = (const float*)d_in[0];
    const float* x_c   = (const float*)d_in[1];
    const float* b_m   = (const float*)d_in[2];
    const float* b_c   = (const float*)d_in[3];
    const float* bb_m  = (const float*)d_in[4];
    const float* bb_c  = (const float*)d_in[5];
    const float* p_m   = (const float*)d_in[6];
    const float* p_c   = (const float*)d_in[7];
    const float* W_xm  = (const float*)d_in[8];
    const float* W_xc  = (const float*)d_in[9];
    const float* W_bm  = (const float*)d_in[10];
    const float* W_bc  = (const float*)d_in[11];
    const float* Wq1_w = (const float*)d_in[12];
    const float* Wq1_b = (const float*)d_in[13];
    const float* Wq2_w = (const float*)d_in[14];
    const float* Wq2_b = (const float*)d_in[15];
    const float* Wk1_w = (const float*)d_in[16];
    const float* Wk1_b = (const float*)d_in[17];
    const float* Wk2_w = (const float*)d_in[18];
    const float* Wk2_b = (const float*)d_in[19];
    const float* mean_w = (const float*)d_in[20];
    const float* mean_b = (const float*)d_in[21];
    const float* cov_w  = (const float*)d_in[22];
    const float* cov_b  = (const float*)d_in[23];
    const float* ln_w   = (const float*)d_in[24];
    const float* ln_b   = (const float*)d_in[25];
    const int*   b_seq  = (const int*)d_in[26];

    float* ws = (float*)d_ws;
    float* qkv = ws;
    float* pq  = ws + 786432;
    float* pk  = ws + 917504;
    float* bbq = ws + 1048576;
    float* bbk = ws + 1064960;
    unsigned short* A_m   = (unsigned short*)(ws + 1081344);
    unsigned short* A_c   = (unsigned short*)(ws + 1212416);
    unsigned short* Wt    = (unsigned short*)(ws + 1343488);
    unsigned short* wm_bf = (unsigned short*)(ws + 2916352);
    unsigned short* wc_bf = (unsigned short*)(ws + 3047424);
    unsigned short* mctxb = (unsigned short*)(ws + 3178496);
    unsigned short* cctxb = (unsigned short*)(ws + 3244032);
    float* out = (float*)d_out;

    k_prep<<<dim3(256), 256, 0, stream>>>(
        x_m, b_m, x_c, b_c, mean_w, cov_w, W_xm, W_xc, W_bm, W_bc,
        p_m, bb_m, Wq2_w, Wq2_b, Wk2_w, Wk2_b, Wq1_w, Wq1_b, Wk1_w, Wk1_b,
        A_m, A_c, wm_bf, wc_bf, Wt, pq, pk, bbq, bbk);
    k_mm<<<dim3(768), 256, 0, stream>>>(A_m, A_c, Wt, qkv);
    k_attn2<<<dim3(128, 4, 2), 128, 0, stream>>>(
        qkv, pq, pk, bbq, bbk, bb_c, p_c, b_seq, out + 262144, mctxb, cctxb);
    k_fin<<<dim3(32), 256, 0, stream>>>(
        mctxb, cctxb, wm_bf, wc_bf, mean_b, cov_b, x_m, x_c, ln_w, ln_b, out);
}

// Round 7
// 191.054 us; speedup vs baseline: 1.3479x; 1.3479x over previous
//
#include <hip/hip_runtime.h>
#include <math.h>

#define B_ 2
#define S_ 128
#define H_ 4
#define DK_ 128
#define NB_ 4
#define D_ 512
#define M_ 256   // B_*S_

typedef __attribute__((ext_vector_type(8))) short short8;
typedef __attribute__((ext_vector_type(4))) float float4v;
typedef __attribute__((ext_vector_type(4))) unsigned short ushort4v;

__device__ __forceinline__ float elu1(float x) {
    return (x > 0.f) ? (x + 1.f) : __expf(x);
}

__device__ __forceinline__ unsigned short f2bf(float f) {
    unsigned u = __float_as_uint(f);
    unsigned r = (u + 0x7FFFu + ((u >> 16) & 1u)) >> 16;
    return (unsigned short)r;
}

// ---------------------------------------------------------------------------
// ws layout (float offsets) — FIXED: Wt needs 6*512*1024 bf16 = 1,572,864 floats
//  qkv    : 786432   @ 0        (q1,k1,v1,q2,k2,v2 each [256,512]; o>=3 elu'd)
//  pq     : 131072   @ 786432
//  pk     : 131072   @ 917504
//  bbq    : 16384    @ 1048576
//  bbk    : 16384    @ 1064960
//  fKm    : 524288   @ 1081344  ([B,H,NB,S,DK])
//  fKs    : 524288   @ 1605632
//  y_m    : 131072   @ 2129920
//  y_c    : 131072   @ 2260992
//  A_m    : 131072   @ 2392064  (bf16 [256][1024])
//  A_c    : 131072   @ 2523136
//  Wt     : 1572864  @ 2654208  (bf16 [6][512][1024], n-major)
//  wm_bf  : 131072   @ 4227072  (bf16 [512][512], [n][k])
//  wc_bf  : 131072   @ 4358144
//  mctxb  : 65536    @ 4489216  (bf16 [256][512])
//  cctxb  : 65536    @ 4554752
//  total  : 4620288 floats = 18.5 MB
// ---------------------------------------------------------------------------

union __attribute__((aligned(16))) PrepSMem {
    unsigned short tile[32][33];
    struct { float ps[2][8][128]; float wsh[2][128][33]; } c;
};

// ① prep: bf16 conversions (vectorized) + weight transpose + small lins.
__global__ __launch_bounds__(256) void k_prep(
    const float* __restrict__ x_m, const float* __restrict__ b_m,
    const float* __restrict__ x_c, const float* __restrict__ b_c,
    const float* __restrict__ mean_w, const float* __restrict__ cov_w,
    const float* __restrict__ W_xm, const float* __restrict__ W_xc,
    const float* __restrict__ W_bm, const float* __restrict__ W_bc,
    const float* __restrict__ p_m, const float* __restrict__ bb_m,
    const float* __restrict__ Wq2, const float* __restrict__ bq2,
    const float* __restrict__ Wk2, const float* __restrict__ bk2,
    const float* __restrict__ Wq1, const float* __restrict__ bq1,
    const float* __restrict__ Wk1, const float* __restrict__ bk1,
    unsigned short* __restrict__ A_m, unsigned short* __restrict__ A_c,
    unsigned short* __restrict__ wm_bf, unsigned short* __restrict__ wc_bf,
    unsigned short* __restrict__ Wt,
    float* __restrict__ pq, float* __restrict__ pk,
    float* __restrict__ bbq, float* __restrict__ bbk)
{
    __shared__ PrepSMem sm;
    const int t = threadIdx.x;
    const int blk = blockIdx.x;
    const int u2 = t >> 7, tl = t & 127;

    // A: bf16 conversions, 4 elems/thread-iter (float4 load, ushort4 store)
    {
#pragma unroll
        for (int u = 0; u < 4; ++u) {
            int cid = u * 65536 + blk * 256 + t;   // chunk of 4 elems
            int job = cid >> 16;
            int off = (cid & 65535) * 4;
            const float* srcp;
            unsigned short* dst;
            if (job <= 1) {
                int m = off >> 10, k = off & 1023;
                if (job == 0) { srcp = (k < 512) ? (x_m + m * 512 + k) : (b_m + m * 512 + k - 512); dst = A_m; }
                else          { srcp = (k < 512) ? (x_c + m * 512 + k) : (b_c + m * 512 + k - 512); dst = A_c; }
            } else if (job == 2) { srcp = mean_w + off; dst = wm_bf; }
            else                 { srcp = cov_w + off;  dst = wc_bf; }
            float4 v = *(const float4*)srcp;
            ushort4v o;
            o.x = f2bf(v.x); o.y = f2bf(v.y); o.z = f2bf(v.z); o.w = f2bf(v.w);
            *(ushort4v*)(dst + off) = o;
        }
    }
    // B: projection-weight transpose+convert -> Wt[o][n][k]
    {
        const int tx = t & 31, ty = t >> 5;
        for (int it = 0; it < 12; ++it) {
            int tid = blk * 12 + it;
            int nt = tid & 15, kt = (tid >> 4) & 15, z = tid >> 8;
            int o = z >> 1, part = z & 1;
            const float* src;
            if (part == 0) src = (o < 3) ? (W_xm + o * 262144) : (W_xc + (o - 3) * 262144);
            else           src = (o < 3) ? (W_bm + o * 262144) : (W_bc + (o - 3) * 262144);
            __syncthreads();
#pragma unroll
            for (int u = 0; u < 4; ++u)
                sm.tile[ty + u * 8][tx] = f2bf(src[(kt * 32 + ty + u * 8) * 512 + nt * 32 + tx]);
            __syncthreads();
            unsigned short* dst = Wt + o * 524288 + part * 512;
#pragma unroll
            for (int u = 0; u < 4; ++u)
                dst[(nt * 32 + ty + u * 8) * 1024 + kt * 32 + tx] = sm.tile[tx][ty + u * 8];
        }
    }
    __syncthreads();
    // C: small 128x128 lins (pq, pk, bbq, bbk); 2 half-block units, blk<144
    if (blk < 144) {
        const int cunit = blk * 2 + u2;
        const float *src, *Wm, *bias; float* dst; int row0;
        if (cunit < 128)      { src = p_m;  Wm = Wq2; bias = bq2; dst = pq;  row0 = cunit * 8; }
        else if (cunit < 256) { src = p_m;  Wm = Wk2; bias = bk2; dst = pk;  row0 = (cunit - 128) * 8; }
        else if (cunit < 272) { src = bb_m; Wm = Wq1; bias = bq1; dst = bbq; row0 = (cunit - 256) * 8; }
        else                  { src = bb_m; Wm = Wk1; bias = bk1; dst = bbk; row0 = (cunit - 272) * 8; }

        float (*ps)[128] = sm.c.ps[u2];
        float (*wsh)[33] = sm.c.wsh[u2];
#pragma unroll
        for (int r = 0; r < 8; ++r) ps[r][tl] = src[(row0 + r) * 128 + tl];

        float acc[8];
#pragma unroll
        for (int r = 0; r < 8; ++r) acc[r] = 0.f;

        const int kc = tl & 31, kr0 = tl >> 5;
        for (int c0 = 0; c0 < 128; c0 += 32) {
            __syncthreads();
#pragma unroll 8
            for (int u = 0; u < 32; ++u)
                wsh[kr0 + u * 4][kc] = Wm[(kr0 + u * 4) * 128 + c0 + kc];
            __syncthreads();
#pragma unroll 8
            for (int k2 = 0; k2 < 32; ++k2) {
                float wvv = wsh[tl][k2];
#pragma unroll
                for (int r = 0; r < 8; ++r)
                    acc[r] = fmaf(ps[r][c0 + k2], wvv, acc[r]);
            }
        }
        float bv = bias[tl];
#pragma unroll
        for (int r = 0; r < 8; ++r) dst[(row0 + r) * 128 + tl] = acc[r] + bv;
    }
}

// ② MFMA projection GEMM: one wave per 16x16 tile, K=1024.
__global__ __launch_bounds__(256) void k_mm(
    const unsigned short* __restrict__ A_m, const unsigned short* __restrict__ A_c,
    const unsigned short* __restrict__ Wt, float* __restrict__ qkv)
{
    const int t = threadIdx.x;
    const int wid = blockIdx.x * 4 + (t >> 6);
    const int lane = t & 63;
    const int o = wid >> 9;
    const int rem = wid & 511;
    const int nt = rem & 31, mt = rem >> 5;
    const int m0 = mt * 16, n0 = nt * 16;
    const int l15 = lane & 15, quad = lane >> 4;

    const unsigned short* A = (o < 3) ? A_m : A_c;
    const unsigned short* ap = A + (m0 + l15) * 1024 + quad * 8;
    const unsigned short* bp = Wt + o * 524288 + (n0 + l15) * 1024 + quad * 8;

    float4v acc0 = {0.f, 0.f, 0.f, 0.f};
    float4v acc1 = {0.f, 0.f, 0.f, 0.f};
#pragma unroll
    for (int k0 = 0; k0 < 1024; k0 += 64) {
        short8 a0 = *(const short8*)(ap + k0);
        short8 b0 = *(const short8*)(bp + k0);
        short8 a1 = *(const short8*)(ap + k0 + 32);
        short8 b1 = *(const short8*)(bp + k0 + 32);
        acc0 = __builtin_amdgcn_mfma_f32_16x16x32_bf16(a0, b0, acc0, 0, 0, 0);
        acc1 = __builtin_amdgcn_mfma_f32_16x16x32_bf16(a1, b1, acc1, 0, 0, 0);
    }

    float* dst = qkv + o * 131072;
#pragma unroll
    for (int r = 0; r < 4; ++r) {
        float v = acc0[r] + acc1[r];
        if (o >= 3) v = elu1(v);
        dst[(m0 + quad * 4 + r) * 512 + n0 + l15] = v;
    }
}

// ③ fK precompute (tri-SAGP, K-side only): block (j, h, b), thread = dim.
//    fK depends on (seq[i], j) — only NB=4 variants per j: S*NB work, not S*S.
__global__ __launch_bounds__(128) void k_fuseK(
    const float* __restrict__ qkv, const float* __restrict__ pk,
    const float* __restrict__ bbk, const float* __restrict__ bb_c,
    const float* __restrict__ p_c, const int* __restrict__ b_seq,
    float* __restrict__ fKm, float* __restrict__ fKs)
{
    const int t = threadIdx.x;
    const int j = blockIdx.x, h = blockIdx.y, b = blockIdx.z;
    const int d = h * 128 + t;
    const float eps = 1e-24f;
    const int base = (b * S_ + j) * D_ + d;
    const int sj = b_seq[b * S_ + j];

    float m1 = qkv[M_ * D_ + base];        // k1
    float c1 = qkv[4 * M_ * D_ + base];    // k2 (elu'd)
    float m3 = pk[base];
    float c3 = p_c[base];

    float p1 = 1.f / fmaxf(c1, eps);
    float p3 = 1.f / fmaxf(c3, eps);
    float mp13 = m1 * p1 + m3 * p3;

#pragma unroll
    for (int sv = 0; sv < 4; ++sv) {
        int idx = (b * 16 + sj * 4 + sv) * 512 + d;   // n1=seq[j], n2=sv(=si)
        float m2 = bbk[idx];
        float c2 = bb_c[idx];
        float p2 = 1.f / fmaxf(c2, eps);
        float cc = 1.f / (p1 + p2 + p3);
        int o = (((b * H_ + h) * 4 + sv) * S_ + j) * 128 + t;   // [B,H,NB,S,DK]
        fKm[o] = cc * (mp13 + m2 * p2);
        fKs[o] = sqrtf(fmaxf(cc, eps));
    }
}

// ④ attn: fQ inline (cheap, once per block) + fK from ws; softmax; ctx.
__global__ __launch_bounds__(128) void k_attn3(
    const float* __restrict__ qkv, const float* __restrict__ pq,
    const float* __restrict__ bbq, const float* __restrict__ bb_c,
    const float* __restrict__ p_c, const int* __restrict__ b_seq,
    const float* __restrict__ fKm, const float* __restrict__ fKs,
    float* __restrict__ probs_out, unsigned short* __restrict__ mctxb,
    unsigned short* __restrict__ cctxb)
{
    const int t = threadIdx.x;
    const int i = blockIdx.x, h = blockIdx.y, b = blockIdx.z;
    const float eps = 1e-24f;

    __shared__ __attribute__((aligned(16))) float qm[4 * 132];
    __shared__ __attribute__((aligned(16))) float qs[4 * 132];
    __shared__ float red[4];
    __shared__ float pr[128], pr2[128];

    const int si = b_seq[b * S_ + i];
    const int sj = b_seq[b * S_ + t];

    // fQ(i, sv) -> LDS (thread t = dim)
    {
        const int d = h * 128 + t;
        const int base = (b * S_ + i) * D_ + d;
        float m1 = qkv[base];                  // q1
        float c1 = qkv[3 * M_ * D_ + base];    // q2 (elu'd)
        float m3 = pq[base];
        float c3 = p_c[base];
        float p1 = 1.f / fmaxf(c1, eps);
        float p3 = 1.f / fmaxf(c3, eps);
        float mp13 = m1 * p1 + m3 * p3;
#pragma unroll
        for (int sv = 0; sv < 4; ++sv) {
            int idx = (b * 16 + sv * 4 + si) * 512 + d;   // n1=sv(=seq[j]), n2=seq[i]
            float m2 = bbq[idx];
            float c2 = bb_c[idx];
            float p2 = 1.f / fmaxf(c2, eps);
            float cc = 1.f / (p1 + p2 + p3);
            qm[sv * 132 + t] = cc * (mp13 + m2 * p2);
            qs[sv * 132 + t] = sqrtf(fmaxf(cc, eps));
        }
    }
    __syncthreads();

    // W2 distance vs fK(si, j=t, :)
    const int krow = (((b * H_ + h) * 4 + si) * S_ + t) * 128;
    const float4* kmp = (const float4*)(fKm + krow);
    const float4* ksp = (const float4*)(fKs + krow);

    float w2 = 0.f;
#pragma unroll 4
    for (int k4 = 0; k4 < 32; ++k4) {
        float4 km = kmp[k4];
        float4 ks = ksp[k4];
        float4 m = *(const float4*)&qm[sj * 132 + k4 * 4];
        float4 s = *(const float4*)&qs[sj * 132 + k4 * 4];
        float d0 = m.x - km.x, d1 = m.y - km.y, d2 = m.z - km.z, d3 = m.w - km.w;
        float e0 = s.x - ks.x, e1 = s.y - ks.y, e2 = s.z - ks.z, e3 = s.w - ks.w;
        w2 += d0 * d0 + d1 * d1 + d2 * d2 + d3 * d3
            + e0 * e0 + e1 * e1 + e2 * e2 + e3 * e3;
    }
    float score = -w2 * 0.08838834764831845f;   // 1/sqrt(128)

    // softmax over 128 threads (2 waves)
    float mx = score;
#pragma unroll
    for (int off = 32; off >= 1; off >>= 1) mx = fmaxf(mx, __shfl_xor(mx, off));
    if ((t & 63) == 0) red[t >> 6] = mx;
    __syncthreads();
    mx = fmaxf(red[0], red[1]);
    float e = __expf(score - mx);
    float sm = e;
#pragma unroll
    for (int off = 32; off >= 1; off >>= 1) sm += __shfl_xor(sm, off);
    if ((t & 63) == 0) red[2 + (t >> 6)] = sm;
    __syncthreads();
    float p = e / (red[2] + red[3]);

    probs_out[((b * H_ + h) * S_ + i) * S_ + t] = p;
    pr[t] = p;
    pr2[t] = p * p;
    __syncthreads();

    // ctx (thread t = dim)
    const float* v1 = qkv + 2 * M_ * D_ + (b * S_) * D_ + h * 128 + t;
    const float* v2 = qkv + 5 * M_ * D_ + (b * S_) * D_ + h * 128 + t;
    float am = 0.f, ac = 0.f;
#pragma unroll 8
    for (int j = 0; j < 128; ++j) {
        am = fmaf(pr[j], v1[j * D_], am);
        ac = fmaf(pr2[j], v2[j * D_], ac);
    }
    mctxb[(b * S_ + i) * D_ + h * 128 + t] = f2bf(am);
    cctxb[(b * S_ + i) * D_ + h * 128 + t] = f2bf(ac);
}

// ⑤ epilogue MFMA GEMM: y[mat][m][n] = sum_k ctx_bf[m][k]*w_bf[n][k].
//    Full K per wave, direct store. 1024 waves (256 blocks).
__global__ __launch_bounds__(256) void k_fin_mm(
    const unsigned short* __restrict__ mctxb, const unsigned short* __restrict__ cctxb,
    const unsigned short* __restrict__ wm_bf, const unsigned short* __restrict__ wc_bf,
    float* __restrict__ y_m, float* __restrict__ y_c)
{
    const int t = threadIdx.x;
    const int wid = blockIdx.x * 4 + (t >> 6);
    const int lane = t & 63;
    const int mat = wid >> 9;
    const int rem = wid & 511;
    const int nt = rem & 31, mt = rem >> 5;
    const int m0 = mt * 16, n0 = nt * 16;
    const int l15 = lane & 15, quad = lane >> 4;

    const unsigned short* A = mat ? cctxb : mctxb;
    const unsigned short* Bw = mat ? wc_bf : wm_bf;
    float* y = mat ? y_c : y_m;

    const unsigned short* ap = A + (m0 + l15) * 512 + quad * 8;
    const unsigned short* bp = Bw + (n0 + l15) * 512 + quad * 8;

    float4v acc0 = {0.f, 0.f, 0.f, 0.f};
    float4v acc1 = {0.f, 0.f, 0.f, 0.f};
#pragma unroll
    for (int k0 = 0; k0 < 512; k0 += 64) {
        short8 a0 = *(const short8*)(ap + k0);
        short8 b0 = *(const short8*)(bp + k0);
        short8 a1 = *(const short8*)(ap + k0 + 32);
        short8 b1 = *(const short8*)(bp + k0 + 32);
        acc0 = __builtin_amdgcn_mfma_f32_16x16x32_bf16(a0, b0, acc0, 0, 0, 0);
        acc1 = __builtin_amdgcn_mfma_f32_16x16x32_bf16(a1, b1, acc1, 0, 0, 0);
    }
#pragma unroll
    for (int r = 0; r < 4; ++r)
        y[(m0 + quad * 4 + r) * 512 + n0 + l15] = acc0[r] + acc1[r];
}

// ⑥ bias + residual + LayerNorm -> out. One block per output row (512 rows).
__global__ __launch_bounds__(256) void k_ln(
    const float* __restrict__ y_m, const float* __restrict__ y_c,
    const float* __restrict__ mean_b, const float* __restrict__ cov_b,
    const float* __restrict__ x_m, const float* __restrict__ x_c,
    const float* __restrict__ ln_w, const float* __restrict__ ln_b,
    float* __restrict__ out)
{
    const int t = threadIdx.x;
    const int id = blockIdx.x;
    const int mat = id >> 8, row = id & 255;
    const float* yg = mat ? y_c : y_m;
    const float* bias = mat ? cov_b : mean_b;
    const float* res = mat ? x_c : x_m;
    const int base = row * 512;

    __shared__ float red[8];

    float y0 = yg[base + t] + bias[t] + res[base + t];
    float y1 = yg[base + 256 + t] + bias[256 + t] + res[base + 256 + t];
    float s = y0 + y1, ss = y0 * y0 + y1 * y1;
#pragma unroll
    for (int off = 32; off >= 1; off >>= 1) { s += __shfl_xor(s, off); ss += __shfl_xor(ss, off); }
    if ((t & 63) == 0) { red[t >> 6] = s; red[4 + (t >> 6)] = ss; }
    __syncthreads();
    float mu = (red[0] + red[1] + red[2] + red[3]) * (1.f / 512.f);
    float var = (red[4] + red[5] + red[6] + red[7]) * (1.f / 512.f) - mu * mu;
    float rstd = 1.f / sqrtf(var + 1e-12f);
    out[mat * 131072 + base + t] = (y0 - mu) * rstd * ln_w[t] + ln_b[t];
    out[mat * 131072 + base + 256 + t] = (y1 - mu) * rstd * ln_w[256 + t] + ln_b[256 + t];
}

extern "C" void kernel_launch(void* const* d_in, const int* in_sizes, int n_in,
                              void* d_out, int out_size, void* d_ws, size_t ws_size,
                              hipStream_t stream) {
    (void)in_sizes; (void)n_in; (void)out_size; (void)ws_size;
    const float* x_m   = (const float*)d_in[0];
    const float* x_c   = (const float*)d_in[1];
    const float* b_m   = (const float*)d_in[2];
    const float* b_c   = (const float*)d_in[3];
    const float* bb_m  = (const float*)d_in[4];
    const float* bb_c  = (const float*)d_in[5];
    const float* p_m   = (const float*)d_in[6];
    const float* p_c   = (const float*)d_in[7];
    const float* W_xm  = (const float*)d_in[8];
    const float* W_xc  = (const float*)d_in[9];
    const float* W_bm  = (const float*)d_in[10];
    const float* W_bc  = (const float*)d_in[11];
    const float* Wq1_w = (const float*)d_in[12];
    const float* Wq1_b = (const float*)d_in[13];
    const float* Wq2_w = (const float*)d_in[14];
    const float* Wq2_b = (const float*)d_in[15];
    const float* Wk1_w = (const float*)d_in[16];
    const float* Wk1_b = (const float*)d_in[17];
    const float* Wk2_w = (const float*)d_in[18];
    const float* Wk2_b = (const float*)d_in[19];
    const float* mean_w = (const float*)d_in[20];
    const float* mean_b = (const float*)d_in[21];
    const float* cov_w  = (const float*)d_in[22];
    const float* cov_b  = (const float*)d_in[23];
    const float* ln_w   = (const float*)d_in[24];
    const float* ln_b   = (const float*)d_in[25];
    const int*   b_seq  = (const int*)d_in[26];

    float* ws = (float*)d_ws;
    float* qkv = ws;
    float* pq  = ws + 786432;
    float* pk  = ws + 917504;
    float* bbq = ws + 1048576;
    float* bbk = ws + 1064960;
    float* fKm = ws + 1081344;
    float* fKs = ws + 1605632;
    float* y_m = ws + 2129920;
    float* y_c = ws + 2260992;
    unsigned short* A_m   = (unsigned short*)(ws + 2392064);
    unsigned short* A_c   = (unsigned short*)(ws + 2523136);
    unsigned short* Wt    = (unsigned short*)(ws + 2654208);
    unsigned short* wm_bf = (unsigned short*)(ws + 4227072);
    unsigned short* wc_bf = (unsigned short*)(ws + 4358144);
    unsigned short* mctxb = (unsigned short*)(ws + 4489216);
    unsigned short* cctxb = (unsigned short*)(ws + 4554752);
    float* out = (float*)d_out;

    k_prep<<<dim3(256), 256, 0, stream>>>(
        x_m, b_m, x_c, b_c, mean_w, cov_w, W_xm, W_xc, W_bm, W_bc,
        p_m, bb_m, Wq2_w, Wq2_b, Wk2_w, Wk2_b, Wq1_w, Wq1_b, Wk1_w, Wk1_b,
        A_m, A_c, wm_bf, wc_bf, Wt, pq, pk, bbq, bbk);
    k_mm<<<dim3(768), 256, 0, stream>>>(A_m, A_c, Wt, qkv);
    k_fuseK<<<dim3(128, 4, 2), 128, 0, stream>>>(
        qkv, pk, bbk, bb_c, p_c, b_seq, fKm, fKs);
    k_attn3<<<dim3(128, 4, 2), 128, 0, stream>>>(
        qkv, pq, bbq, bb_c, p_c, b_seq, fKm, fKs, out + 262144, mctxb, cctxb);
    k_fin_mm<<<dim3(256), 256, 0, stream>>>(
        mctxb, cctxb, wm_bf, wc_bf, y_m, y_c);
    k_ln<<<dim3(512), 256, 0, stream>>>(
        y_m, y_c, mean_b, cov_b, x_m, x_c, ln_w, ln_b, out);
}